// Round 11
// baseline (286.130 us; speedup 1.0000x reference)
//
#include <hip/hip_runtime.h>

// y[m,o] = sum_k x[m,k] * (W[o,k] + dW[o,k]) + bias[o],  W int4-dequant.
// M=8192, N=4096(OUT), K=4096(IN).
//
// Round 11: B out of LDS. 256x256 tile, bf16 16x16x32, frag-packed (r10
// packs unchanged). LDS holds A only: 4 bufs x 32KB, stage distance 2.
// B fragments load global->register (lane-linear, coalesced; L1 merges the
// 2 waves sharing a quarter). LDS traffic/K-tile: 256KB -> 160KB, dropping
// the LDS port below the MFMA pipe (the r10 co-bottleneck).
// Sync: 1 raw s_barrier per K-tile; no vmcnt full stops. Guarantees:
//  - stage(t) issues FIRST in body t-2 (sched-fenced); 12 VMEM/body =>
//    exactly 20 VMEM issue after it by the end of body t-1; WAITV(20)
//    before barrier(t-1) + in-order vmcnt retire => stage(t) landed.
//  - own-body ds_reads retire before own MFMAs (compiler lgkm waits),
//    hence before the barrier; stages target a buf last read 2 bodies ago.
//  - B regs: compiler per-register vmcnt waits; b23 WAR = reg dependency.

#define M_DIM 8192
#define N_DIM 4096
#define K_DIM 4096
#define NUMEL (N_DIM * K_DIM)

typedef _Float16 half_t;
typedef __attribute__((ext_vector_type(4))) _Float16 half4v;
typedef __attribute__((ext_vector_type(8))) _Float16 half8v;
typedef __attribute__((ext_vector_type(8))) short short8v;
typedef __attribute__((ext_vector_type(8))) unsigned short ushort8v;
typedef __attribute__((ext_vector_type(4))) float float4v;
typedef __attribute__((ext_vector_type(4))) int int4v;

#define KTILES 64
#define LDT 72

static __device__ __forceinline__ void gload16(const void* g, void* l) {
    __builtin_amdgcn_global_load_lds(
        (const __attribute__((address_space(1))) void*)g,
        (__attribute__((address_space(3))) void*)l, 16, 0, 0);
}

static __device__ __forceinline__ unsigned short f2bf(float f) {
    unsigned u = __builtin_bit_cast(unsigned, f);
    u += 0x7fffu + ((u >> 16) & 1u);
    return (unsigned short)(u >> 16);
}

// ---------- Phase 1a: dequant+delta -> bf16, fragment-packed (r10) ---------
__global__ __launch_bounds__(256) void k_pack_w(
    const int* __restrict__ qp, const float* __restrict__ sc,
    const float* __restrict__ zr, const float* __restrict__ dwt,
    unsigned char* __restrict__ Wp)
{
    const size_t o = ((size_t)blockIdx.x * 256 + threadIdx.x) << 4;
    const int chunk16 = (int)(o >> 14);
    const int c  = (int)(o >> 10) & 15;
    const int ln = (int)(o >> 4) & 63;
    const int n = (chunk16 >> 6) * 128 + (c >> 1) * 16 + (ln & 15);
    const int k = (chunk16 & 63) * 64 + (c & 1) * 32 + (ln >> 4) * 8;
    const long flat = (long)n * K_DIM + k;
    const int g = n * 32 + (k >> 7);
    const float s = sc[g];
    const float zs = zr[g] * s;
    int4v q4 = *(const int4v*)(qp + (flat >> 1));
    float4v d0 = *(const float4v*)(dwt + flat);
    float4v d1 = *(const float4v*)(dwt + flat + 4);
    float d[8] = {d0[0], d0[1], d0[2], d0[3], d1[0], d1[1], d1[2], d1[3]};
    ushort8v vh;
#pragma unroll
    for (int j = 0; j < 4; ++j) {
        vh[2*j]   = f2bf(fmaf((float)(q4[j] & 15),        s, d[2*j]   - zs));
        vh[2*j+1] = f2bf(fmaf((float)((q4[j] >> 4) & 15), s, d[2*j+1] - zs));
    }
    *(ushort8v*)(Wp + o) = vh;
}

// ---------- Phase 1b: x fp32 -> bf16, fragment-packed (r10) ----------
__global__ __launch_bounds__(256) void k_pack_x(
    const float* __restrict__ X, unsigned char* __restrict__ Xp)
{
    const size_t o = ((size_t)blockIdx.x * 256 + threadIdx.x) << 4;
    const int chunk16 = (int)(o >> 14);
    const int c  = (int)(o >> 10) & 15;
    const int ln = (int)(o >> 4) & 63;
    const int m = (chunk16 >> 6) * 128 + (c >> 1) * 16 + (ln & 15);
    const int k = (chunk16 & 63) * 64 + (c & 1) * 32 + (ln >> 4) * 8;
    const float* src = X + (size_t)m * K_DIM + k;
    float4v x0 = *(const float4v*)(src);
    float4v x1 = *(const float4v*)(src + 4);
    ushort8v vh;
    vh[0] = f2bf(x0[0]); vh[1] = f2bf(x0[1]);
    vh[2] = f2bf(x0[2]); vh[3] = f2bf(x0[3]);
    vh[4] = f2bf(x1[0]); vh[5] = f2bf(x1[1]);
    vh[6] = f2bf(x1[2]); vh[7] = f2bf(x1[3]);
    *(ushort8v*)(Xp + o) = vh;
}

// ---------- GEMM: A via LDS (4 bufs), B via global->reg ----------
#define BARX() do { __builtin_amdgcn_sched_barrier(0); \
                    __builtin_amdgcn_s_barrier(); \
                    __builtin_amdgcn_sched_barrier(0); } while(0)
#define WAITV_(N) do { __builtin_amdgcn_sched_barrier(0); \
                       asm volatile("s_waitcnt vmcnt(" #N ")" ::: "memory"); \
                       __builtin_amdgcn_sched_barrier(0); } while(0)
#define WAITV(N) WAITV_(N)

// stage K-tile T's two A halves into buf (4 gload16/thread)
#define STAGE_A(BUF, T) do { \
    const unsigned char* s0_ = ap0 + ((size_t)(T) << 14); \
    const unsigned char* s1_ = ap1 + ((size_t)(T) << 14); \
    gload16(s0_,        &lds4[BUF][t16]); \
    gload16(s0_ + 8192, &lds4[BUF][t16 + 8192]); \
    gload16(s1_,        &lds4[BUF][16384 + t16]); \
    gload16(s1_ + 8192, &lds4[BUF][16384 + t16 + 8192]); \
} while(0)

#define LOADB01(SET, T) do { \
_Pragma("unroll") for (int j_ = 0; j_ < 2; ++j_) \
_Pragma("unroll") for (int ks_ = 0; ks_ < 2; ++ks_) \
        SET[j_][ks_] = *(const short8v*)(bgl + ((size_t)(T) << 14) \
                                             + ((j_ * 2 + ks_) << 10)); \
} while(0)

#define LOADB23(T) do { \
_Pragma("unroll") for (int j_ = 0; j_ < 2; ++j_) \
_Pragma("unroll") for (int ks_ = 0; ks_ < 2; ++ks_) \
        b23[j_][ks_] = *(const short8v*)(bgl + ((size_t)(T) << 14) \
                                             + (((2 + j_) * 2 + ks_) << 10)); \
} while(0)

#define READ_A(BUF, F0) do { \
_Pragma("unroll") for (int i_ = 0; i_ < 4; ++i_) \
_Pragma("unroll") for (int ks_ = 0; ks_ < 2; ++ks_) \
        ah[i_][ks_] = *(const short8v*)(&lds4[BUF] \
            [awm + ((((F0) + i_) * 2 + ks_) << 10) + lane16]); \
} while(0)

#define MFMA_Q(F0, N0, BREG) do { \
    __builtin_amdgcn_s_setprio(1); \
_Pragma("unroll") for (int i_ = 0; i_ < 4; ++i_) \
_Pragma("unroll") for (int j_ = 0; j_ < 2; ++j_) \
_Pragma("unroll") for (int ks_ = 0; ks_ < 2; ++ks_) \
        acc[(F0)+i_][(N0)+j_] = __builtin_amdgcn_mfma_f32_16x16x32_bf16( \
            ah[i_][ks_], BREG[j_][ks_], acc[(F0)+i_][(N0)+j_], 0, 0, 0); \
    __builtin_amdgcn_s_setprio(0); \
} while(0)

// body for K-tile T: read buf RBUF, stage T+2 -> SBUF, load B(T+1)
// BCUR = this tile's b01 set, BNXT = the other set. 12 VMEM ops when STG&&LDB.
#define BODY(RBUF, SBUF, BCUR, BNXT, T, STG, LDB, WVN) do { \
    if (STG) { STAGE_A(SBUF, (T) + 2); } \
    __builtin_amdgcn_sched_barrier(0); \
    if (LDB) { LOADB01(BNXT, (T) + 1); } \
    READ_A(RBUF, 0); \
    MFMA_Q(0, 0, BCUR); \
    MFMA_Q(0, 2, b23); \
    READ_A(RBUF, 4); \
    MFMA_Q(4, 2, b23); \
    if (LDB) { LOADB23((T) + 1); } \
    MFMA_Q(4, 0, BCUR); \
    WAITV(WVN); \
    BARX(); \
} while(0)

__global__ __launch_bounds__(512, 2) void k_gemm_breg(
    const unsigned char* __restrict__ Apk, const unsigned char* __restrict__ Bpk,
    const float* __restrict__ bias, float* __restrict__ Y)
{
    __shared__ __align__(16) unsigned char lds4[4][32768];  // A only

    const int tid  = threadIdx.x;
    const int lane = tid & 63;
    const int wave = tid >> 6;
    const int wm = wave >> 2;              // A half
    const int wn = wave & 3;               // B quarter
    const int lane16 = lane << 4;
    const int t16 = tid << 4;
    const int awm = wm << 14;

    const int wg = blockIdx.x;
    const int swg = (wg & 7) * 64 + (wg >> 3);   // 512 blocks, 8 XCDs, bijective
    const int bn = swg & 15;
    const int bm = swg >> 4;

    const unsigned char* ap0 = Apk + (((size_t)(2 * bm)     * KTILES) << 14) + t16;
    const unsigned char* ap1 = Apk + (((size_t)(2 * bm + 1) * KTILES) << 14) + t16;
    const unsigned char* bgl = Bpk + (((size_t)(2 * bn + (wn >> 1)) * KTILES) << 14)
                             + ((wn & 1) << 13) + lane16;

    short8v ah[4][2], b01A[2][2], b01B[2][2], b23[2][2];
    float4v acc[8][4];
    const float4v zero4 = {0.f, 0.f, 0.f, 0.f};
#pragma unroll
    for (int i = 0; i < 8; ++i)
#pragma unroll
        for (int j = 0; j < 4; ++j) acc[i][j] = zero4;

    // ---- prologue: stage tiles 0,1 (bufs 0,1); B(0) -> regs ----
    STAGE_A(0, 0);
    STAGE_A(1, 1);
    __builtin_amdgcn_sched_barrier(0);
    LOADB01(b01A, 0);
    LOADB23(0);
    WAITV(12);                 // stage(0) done (12 newer may fly)
    BARX();

    // ---- 15 x 4 bodies: t = 0..59 (stages to 61, B to 60) ----
    for (int it = 0; it < 15; ++it) {
        const int t0 = it << 2;
        BODY(0, 2, b01A, b01B, t0,     1, 1, 20);
        BODY(1, 3, b01B, b01A, t0 + 1, 1, 1, 20);
        BODY(2, 0, b01A, b01B, t0 + 2, 1, 1, 20);
        BODY(3, 1, b01B, b01A, t0 + 3, 1, 1, 20);
    }
    // ---- tail ----
    BODY(0, 2, b01A, b01B, 60, 1, 1, 20);   // stage 62, B 61
    BODY(1, 3, b01B, b01A, 61, 1, 1, 20);   // stage 63, B 62
    BODY(2, 0, b01A, b01B, 62, 0, 1, 8);    // B 63; WAITV(8) => stage63 done
    // t = 63: no stage/load/barrier
    READ_A(3, 0);
    MFMA_Q(0, 0, b01B);
    MFMA_Q(0, 2, b23);
    READ_A(3, 4);
    MFMA_Q(4, 2, b23);
    MFMA_Q(4, 0, b01B);

    // ---- epilogue: 16x16 C/D map col=lane&15, row=(lane>>4)*4+reg ----
    const long m0 = (long)bm * 256 + wm * 128;
    const long n0 = (long)bn * 256 + wn * 64;
#pragma unroll
    for (int mf = 0; mf < 8; ++mf) {
        const long row = m0 + mf * 16 + (lane >> 4) * 4;
#pragma unroll
        for (int nf = 0; nf < 4; ++nf) {
            const long col = n0 + nf * 16 + (lane & 15);
            const float b = bias[col];
#pragma unroll
            for (int r = 0; r < 4; ++r)
                Y[(row + r) * N_DIM + col] = acc[mf][nf][r] + b;
        }
    }
}

// ---------- fallback (no workspace): fused dequant 128x128 GEMM ----------
__global__ __launch_bounds__(256, 2) void k_gemm_fused(
    const float* __restrict__ X, const int* __restrict__ qp,
    const float* __restrict__ sc, const float* __restrict__ zr,
    const float* __restrict__ dwt,
    const float* __restrict__ bias, float* __restrict__ Y)
{
    __shared__ __align__(16) half_t Ah[128 * LDT];
    __shared__ __align__(16) half_t Bh[128 * LDT];

    const int tid  = threadIdx.x;
    const int lane = tid & 63;
    const int wave = tid >> 6;
    const int wm = wave >> 1, wn = wave & 1;
    const int bn = blockIdx.x & 31;
    const int bm = blockIdx.x >> 5;
    const long m0 = (long)bm * 128;
    const long n0 = (long)bn * 128;
    const int fr = lane & 15;
    const int ko = (lane >> 4) * 8;

    const float4v zero4 = {0.f, 0.f, 0.f, 0.f};
    float4v acc[4][4];
#pragma unroll
    for (int i = 0; i < 4; ++i)
#pragma unroll
        for (int j = 0; j < 4; ++j) acc[i][j] = zero4;

    for (int k0 = 0; k0 < K_DIM; k0 += 64) {
        {
            const int ar = tid >> 4;
            const int ac = (tid & 15) * 4;
#pragma unroll
            for (int rr = 0; rr < 8; ++rr) {
                const int row = ar + rr * 16;
                float4v xv = *(const float4v*)(X + (m0 + row) * K_DIM + k0 + ac);
                half4v h;
#pragma unroll
                for (int j = 0; j < 4; ++j) h[j] = (half_t)xv[j];
                *(half4v*)(Ah + row * LDT + ac) = h;
            }
        }
        {
            const int cr = tid >> 3;
            const int cc = (tid & 7) * 8;
#pragma unroll
            for (int rr = 0; rr < 4; ++rr) {
                const int row = cr + rr * 32;
                const long n = n0 + row;
                const int g = (int)(n * 32 + (k0 >> 7));
                const float s = sc[g];
                const float zs = zr[g] * s;
                const long flat = n * K_DIM + k0 + cc;
                int4v q4 = *(const int4v*)(qp + (flat >> 1));
                float4v d0 = *(const float4v*)(dwt + flat);
                float4v d1 = *(const float4v*)(dwt + flat + 4);
                float d[8] = {d0[0], d0[1], d0[2], d0[3], d1[0], d1[1], d1[2], d1[3]};
                half8v vh;
#pragma unroll
                for (int j = 0; j < 4; ++j) {
                    vh[2*j]   = (half_t)fmaf((float)(q4[j] & 15),        s, d[2*j]   - zs);
                    vh[2*j+1] = (half_t)fmaf((float)((q4[j] >> 4) & 15), s, d[2*j+1] - zs);
                }
                *(half8v*)(Bh + row * LDT + cc) = vh;
            }
        }
        __syncthreads();
#pragma unroll
        for (int ks = 0; ks < 2; ++ks) {
            const int kk = ks * 32 + ko;
            half8v a2[4], b2[4];
#pragma unroll
            for (int i = 0; i < 4; ++i) {
                a2[i] = *(const half8v*)(Ah + (wm * 64 + i * 16 + fr) * LDT + kk);
                b2[i] = *(const half8v*)(Bh + (wn * 64 + i * 16 + fr) * LDT + kk);
            }
#pragma unroll
            for (int i = 0; i < 4; ++i)
#pragma unroll
                for (int j = 0; j < 4; ++j)
                    acc[i][j] = __builtin_amdgcn_mfma_f32_16x16x32_f16(
                        a2[i], b2[j], acc[i][j], 0, 0, 0);
        }
        __syncthreads();
    }

#pragma unroll
    for (int i = 0; i < 4; ++i) {
        const long mrow = m0 + wm * 64 + i * 16 + (lane >> 4) * 4;
#pragma unroll
        for (int j = 0; j < 4; ++j) {
            const long col = n0 + wn * 64 + j * 16 + (lane & 15);
            const float b = bias[col];
#pragma unroll
            for (int r = 0; r < 4; ++r)
                Y[(mrow + r) * N_DIM + col] = acc[i][j][r] + b;
        }
    }
}

extern "C" void kernel_launch(void* const* d_in, const int* in_sizes, int n_in,
                              void* d_out, int out_size, void* d_ws, size_t ws_size,
                              hipStream_t stream)
{
    const float* X  = (const float*)d_in[0];
    const int*   qp = (const int*)d_in[1];
    const float* sc = (const float*)d_in[2];
    const float* zr = (const float*)d_in[3];
    const float* dwt = (const float*)d_in[4];
    const float* bs = (const float*)d_in[5];
    float* Y = (float*)d_out;

    const size_t needB = (size_t)N_DIM * K_DIM * 2;   // 33.5 MB
    const size_t needA = (size_t)M_DIM * K_DIM * 2;   // 67.1 MB

    if (ws_size >= needA + needB) {
        unsigned char* Bpk = (unsigned char*)d_ws;
        unsigned char* Apk = Bpk + needB;
        k_pack_w<<<dim3((unsigned)(needB >> 12)), dim3(256), 0, stream>>>(qp, sc, zr, dwt, Bpk);
        k_pack_x<<<dim3((unsigned)(needA >> 12)), dim3(256), 0, stream>>>(X, Apk);
        k_gemm_breg<<<dim3((M_DIM / 256) * (N_DIM / 256)), dim3(512), 0, stream>>>(Apk, Bpk, bs, Y);
    } else {
        k_gemm_fused<<<dim3((M_DIM / 128) * (N_DIM / 128)), dim3(256), 0, stream>>>(
            X, qp, sc, zr, dwt, bs, Y);
    }
}

// Round 12
// 279.997 us; speedup vs baseline: 1.0219x; 1.0219x over previous
//
#include <hip/hip_runtime.h>

// y[m,o] = sum_k x[m,k] * (W[o,k] + dW[o,k]) + bias[o],  W int4-dequant.
// M=8192, N=4096(OUT), K=4096(IN).
//
// Round 12: 256x256 bf16 16x16x32, BK=32 bodies, 4 LDS bufs x 32KB,
// ONE barrier + ONE counted WAITV(8) per body, evenly spaced:
//   body t = [STAGE(t+2 -> buf[(t+2)&3]); WAITV(8); BAR; reads+MFMA buf[t&3]]
// Full read+MFMA region between consecutive barriers -> max wave drift
// (LDS port and MFMA pipe overlap across the 2 waves/SIMD).
// Depth-2 prefetch: stage->wait distance = 2 bodies (~2000cyc >> HBM 900).
// Race-proof: stage(t+2) targets buf last read in body t-2; those reads are
// MFMA-consumed (lgkm) before that wave reaches BAR(t-1); stage issues only
// after BAR(t-1). 4 VMEM/body => WAITV(8) leaves {t+1,t+2} in flight.
// Pack kernels: r10 fragment format, unchanged (validated, conflict-free).

#define M_DIM 8192
#define N_DIM 4096
#define K_DIM 4096
#define NUMEL (N_DIM * K_DIM)

typedef _Float16 half_t;
typedef __attribute__((ext_vector_type(4))) _Float16 half4v;
typedef __attribute__((ext_vector_type(8))) _Float16 half8v;
typedef __attribute__((ext_vector_type(8))) short short8v;
typedef __attribute__((ext_vector_type(8))) unsigned short ushort8v;
typedef __attribute__((ext_vector_type(4))) float float4v;
typedef __attribute__((ext_vector_type(4))) int int4v;

#define KTILES 64                // 64-K packed tiles per 128-row panel
#define LDT 72

static __device__ __forceinline__ void gload16(const void* g, void* l) {
    __builtin_amdgcn_global_load_lds(
        (const __attribute__((address_space(1))) void*)g,
        (__attribute__((address_space(3))) void*)l, 16, 0, 0);
}

static __device__ __forceinline__ unsigned short f2bf(float f) {
    unsigned u = __builtin_bit_cast(unsigned, f);
    u += 0x7fffu + ((u >> 16) & 1u);
    return (unsigned short)(u >> 16);
}

// ---------- Phase 1a: dequant+delta -> bf16, fragment-packed (r10) ---------
__global__ __launch_bounds__(256) void k_pack_w(
    const int* __restrict__ qp, const float* __restrict__ sc,
    const float* __restrict__ zr, const float* __restrict__ dwt,
    unsigned char* __restrict__ Wp)
{
    const size_t o = ((size_t)blockIdx.x * 256 + threadIdx.x) << 4;
    const int chunk16 = (int)(o >> 14);
    const int c  = (int)(o >> 10) & 15;
    const int ln = (int)(o >> 4) & 63;
    const int n = (chunk16 >> 6) * 128 + (c >> 1) * 16 + (ln & 15);
    const int k = (chunk16 & 63) * 64 + (c & 1) * 32 + (ln >> 4) * 8;
    const long flat = (long)n * K_DIM + k;
    const int g = n * 32 + (k >> 7);
    const float s = sc[g];
    const float zs = zr[g] * s;
    int4v q4 = *(const int4v*)(qp + (flat >> 1));
    float4v d0 = *(const float4v*)(dwt + flat);
    float4v d1 = *(const float4v*)(dwt + flat + 4);
    float d[8] = {d0[0], d0[1], d0[2], d0[3], d1[0], d1[1], d1[2], d1[3]};
    ushort8v vh;
#pragma unroll
    for (int j = 0; j < 4; ++j) {
        vh[2*j]   = f2bf(fmaf((float)(q4[j] & 15),        s, d[2*j]   - zs));
        vh[2*j+1] = f2bf(fmaf((float)((q4[j] >> 4) & 15), s, d[2*j+1] - zs));
    }
    *(ushort8v*)(Wp + o) = vh;
}

// ---------- Phase 1b: x fp32 -> bf16, fragment-packed (r10) ----------
__global__ __launch_bounds__(256) void k_pack_x(
    const float* __restrict__ X, unsigned char* __restrict__ Xp)
{
    const size_t o = ((size_t)blockIdx.x * 256 + threadIdx.x) << 4;
    const int chunk16 = (int)(o >> 14);
    const int c  = (int)(o >> 10) & 15;
    const int ln = (int)(o >> 4) & 63;
    const int m = (chunk16 >> 6) * 128 + (c >> 1) * 16 + (ln & 15);
    const int k = (chunk16 & 63) * 64 + (c & 1) * 32 + (ln >> 4) * 8;
    const float* src = X + (size_t)m * K_DIM + k;
    float4v x0 = *(const float4v*)(src);
    float4v x1 = *(const float4v*)(src + 4);
    ushort8v vh;
    vh[0] = f2bf(x0[0]); vh[1] = f2bf(x0[1]);
    vh[2] = f2bf(x0[2]); vh[3] = f2bf(x0[3]);
    vh[4] = f2bf(x1[0]); vh[5] = f2bf(x1[1]);
    vh[6] = f2bf(x1[2]); vh[7] = f2bf(x1[3]);
    *(ushort8v*)(Xp + o) = vh;
}

// ---------- GEMM: BK=32 bodies, 4 bufs, 1 bar/body ----------
#define BARX() do { __builtin_amdgcn_sched_barrier(0); \
                    __builtin_amdgcn_s_barrier(); \
                    __builtin_amdgcn_sched_barrier(0); } while(0)
#define WAITV(N) do { __builtin_amdgcn_sched_barrier(0); \
                      asm volatile("s_waitcnt vmcnt(" #N ")" ::: "memory"); \
                      __builtin_amdgcn_sched_barrier(0); } while(0)

// stage 32-K sub-tile T into buffer BUF (4 gload16/thread, 32KB total)
// packed-tile source offset: kt=T>>1 (16KB tiles), ks=T&1 selects 1KB-chunk
// parity (chunks rt*2+ks, stride 2KB); thread covers (tid>>6)=rt, (tid&63) slot.
#define STAGE32(BUF, T) do { \
    const size_t ko_ = ((size_t)((T) >> 1) << 14) + (size_t)(((T) & 1) << 10) + soff; \
    gload16(a0s + ko_, &lds4[BUF][t16]); \
    gload16(a1s + ko_, &lds4[BUF][8192 + t16]); \
    gload16(b0s + ko_, &lds4[BUF][16384 + t16]); \
    gload16(b1s + ko_, &lds4[BUF][24576 + t16]); \
} while(0)

// A frags i0..i0+3 (m-tiles) of this wave's half; reuse af[0..3]
#define RD_A4(BUF, I0) do { \
_Pragma("unroll") for (int i_ = 0; i_ < 4; ++i_) \
        af[i_] = *(const short8v*)(&lds4[BUF][aoff + (((I0) + i_) << 10)]); \
} while(0)

// B frags j = 0..3 of this wave's quarter
#define RD_B4(BUF) do { \
_Pragma("unroll") for (int j_ = 0; j_ < 4; ++j_) \
        bf[j_] = *(const short8v*)(&lds4[BUF][boff + (j_ << 10)]); \
} while(0)

#define MF16(A0) do { \
    __builtin_amdgcn_s_setprio(1); \
_Pragma("unroll") for (int i_ = 0; i_ < 4; ++i_) \
_Pragma("unroll") for (int j_ = 0; j_ < 4; ++j_) \
        acc[(A0)+i_][j_] = __builtin_amdgcn_mfma_f32_16x16x32_bf16( \
            af[i_], bf[j_], acc[(A0)+i_][j_], 0, 0, 0); \
    __builtin_amdgcn_s_setprio(0); \
} while(0)

// body: read buf RB (tile T), stage T+2 into SB (if STG), counted wait, bar
#define BODY(RB, SB, T, STG, WVN) do { \
    if (STG) { STAGE32(SB, (T) + 2); } \
    WAITV(WVN); \
    BARX(); \
    RD_A4(RB, 0); RD_B4(RB); \
    MF16(0); \
    RD_A4(RB, 4); \
    MF16(4); \
} while(0)

__global__ __launch_bounds__(512, 2) void k_gemm_b32(
    const unsigned char* __restrict__ Apk, const unsigned char* __restrict__ Bpk,
    const float* __restrict__ bias, float* __restrict__ Y)
{
    // [buf][ A: panel0 8K | panel1 8K | B: panel0 8K | panel1 8K ]
    __shared__ __align__(16) unsigned char lds4[4][32768];

    const int tid  = threadIdx.x;
    const int lane = tid & 63;
    const int wave = tid >> 6;
    const int wm = wave >> 2;              // A half (128 rows)
    const int wn = wave & 3;               // B quarter (64 cols)
    const int lane16 = lane << 4;
    const int t16 = tid << 4;
    const int aoff = (wm << 13) + lane16;                          // A panel
    const int boff = 16384 + ((wn >> 1) << 13) + ((wn & 1) << 12) + lane16;

    const int wg = blockIdx.x;
    const int swg = (wg & 7) * 64 + (wg >> 3);   // 512 blocks, 8 XCDs, bijective
    const int bn = swg & 15;
    const int bm = swg >> 4;

    // per-thread stage source bases (rt = tid>>6 -> chunk*2KB, slot = tid&63)
    const size_t soff = ((size_t)(tid >> 6) << 11) + (size_t)((tid & 63) << 4);
    const unsigned char* a0s = Apk + (((size_t)(2 * bm)     * KTILES) << 14);
    const unsigned char* a1s = Apk + (((size_t)(2 * bm + 1) * KTILES) << 14);
    const unsigned char* b0s = Bpk + (((size_t)(2 * bn)     * KTILES) << 14);
    const unsigned char* b1s = Bpk + (((size_t)(2 * bn + 1) * KTILES) << 14);

    short8v af[4], bf[4];
    float4v acc[8][4];
    const float4v zero4 = {0.f, 0.f, 0.f, 0.f};
#pragma unroll
    for (int i = 0; i < 8; ++i)
#pragma unroll
        for (int j = 0; j < 4; ++j) acc[i][j] = zero4;

    // ---- prologue: stage sub-tiles 0 (buf0), 1 (buf1) ----
    STAGE32(0, 0);
    STAGE32(1, 1);
    WAITV(4);                  // tile0 resident; tile1's 4 in flight

    // ---- 31 x 4 bodies: t = 0..123 (stages 2..125) ----
    for (int it = 0; it < 31; ++it) {
        const int t0 = it << 2;
        BODY(0, 2, t0,     1, 8);
        BODY(1, 3, t0 + 1, 1, 8);
        BODY(2, 0, t0 + 2, 1, 8);
        BODY(3, 1, t0 + 3, 1, 8);
    }
    // ---- tail: t = 124..127 ----
    BODY(0, 2, 124, 1, 8);     // stage 126
    BODY(1, 3, 125, 1, 8);     // stage 127
    BODY(2, 0, 126, 0, 4);
    BODY(3, 0, 127, 0, 0);

    // ---- epilogue: 16x16 C/D map col=lane&15, row=(lane>>4)*4+reg ----
    const long m0 = (long)bm * 256 + wm * 128;
    const long n0 = (long)bn * 256 + wn * 64;
#pragma unroll
    for (int mf = 0; mf < 8; ++mf) {
        const long row = m0 + mf * 16 + (lane >> 4) * 4;
#pragma unroll
        for (int nf = 0; nf < 4; ++nf) {
            const long col = n0 + nf * 16 + (lane & 15);
            const float b = bias[col];
#pragma unroll
            for (int r = 0; r < 4; ++r)
                Y[(row + r) * N_DIM + col] = acc[mf][nf][r] + b;
        }
    }
}

// ---------- fallback (no workspace): fused dequant 128x128 GEMM ----------
__global__ __launch_bounds__(256, 2) void k_gemm_fused(
    const float* __restrict__ X, const int* __restrict__ qp,
    const float* __restrict__ sc, const float* __restrict__ zr,
    const float* __restrict__ dwt,
    const float* __restrict__ bias, float* __restrict__ Y)
{
    __shared__ __align__(16) half_t Ah[128 * LDT];
    __shared__ __align__(16) half_t Bh[128 * LDT];

    const int tid  = threadIdx.x;
    const int lane = tid & 63;
    const int wave = tid >> 6;
    const int wm = wave >> 1, wn = wave & 1;
    const int bn = blockIdx.x & 31;
    const int bm = blockIdx.x >> 5;
    const long m0 = (long)bm * 128;
    const long n0 = (long)bn * 128;
    const int fr = lane & 15;
    const int ko = (lane >> 4) * 8;

    const float4v zero4 = {0.f, 0.f, 0.f, 0.f};
    float4v acc[4][4];
#pragma unroll
    for (int i = 0; i < 4; ++i)
#pragma unroll
        for (int j = 0; j < 4; ++j) acc[i][j] = zero4;

    for (int k0 = 0; k0 < K_DIM; k0 += 64) {
        {
            const int ar = tid >> 4;
            const int ac = (tid & 15) * 4;
#pragma unroll
            for (int rr = 0; rr < 8; ++rr) {
                const int row = ar + rr * 16;
                float4v xv = *(const float4v*)(X + (m0 + row) * K_DIM + k0 + ac);
                half4v h;
#pragma unroll
                for (int j = 0; j < 4; ++j) h[j] = (half_t)xv[j];
                *(half4v*)(Ah + row * LDT + ac) = h;
            }
        }
        {
            const int cr = tid >> 3;
            const int cc = (tid & 7) * 8;
#pragma unroll
            for (int rr = 0; rr < 4; ++rr) {
                const int row = cr + rr * 32;
                const long n = n0 + row;
                const int g = (int)(n * 32 + (k0 >> 7));
                const float s = sc[g];
                const float zs = zr[g] * s;
                const long flat = n * K_DIM + k0 + cc;
                int4v q4 = *(const int4v*)(qp + (flat >> 1));
                float4v d0 = *(const float4v*)(dwt + flat);
                float4v d1 = *(const float4v*)(dwt + flat + 4);
                float d[8] = {d0[0], d0[1], d0[2], d0[3], d1[0], d1[1], d1[2], d1[3]};
                half8v vh;
#pragma unroll
                for (int j = 0; j < 4; ++j) {
                    vh[2*j]   = (half_t)fmaf((float)(q4[j] & 15),        s, d[2*j]   - zs);
                    vh[2*j+1] = (half_t)fmaf((float)((q4[j] >> 4) & 15), s, d[2*j+1] - zs);
                }
                *(half8v*)(Bh + row * LDT + cc) = vh;
            }
        }
        __syncthreads();
#pragma unroll
        for (int ks = 0; ks < 2; ++ks) {
            const int kk = ks * 32 + ko;
            half8v a2[4], b2[4];
#pragma unroll
            for (int i = 0; i < 4; ++i) {
                a2[i] = *(const half8v*)(Ah + (wm * 64 + i * 16 + fr) * LDT + kk);
                b2[i] = *(const half8v*)(Bh + (wn * 64 + i * 16 + fr) * LDT + kk);
            }
#pragma unroll
            for (int i = 0; i < 4; ++i)
#pragma unroll
                for (int j = 0; j < 4; ++j)
                    acc[i][j] = __builtin_amdgcn_mfma_f32_16x16x32_f16(
                        a2[i], b2[j], acc[i][j], 0, 0, 0);
        }
        __syncthreads();
    }

#pragma unroll
    for (int i = 0; i < 4; ++i) {
        const long mrow = m0 + wm * 64 + i * 16 + (lane >> 4) * 4;
#pragma unroll
        for (int j = 0; j < 4; ++j) {
            const long col = n0 + wn * 64 + j * 16 + (lane & 15);
            const float b = bias[col];
#pragma unroll
            for (int r = 0; r < 4; ++r)
                Y[(mrow + r) * N_DIM + col] = acc[i][j][r] + b;
        }
    }
}

extern "C" void kernel_launch(void* const* d_in, const int* in_sizes, int n_in,
                              void* d_out, int out_size, void* d_ws, size_t ws_size,
                              hipStream_t stream)
{
    const float* X  = (const float*)d_in[0];
    const int*   qp = (const int*)d_in[1];
    const float* sc = (const float*)d_in[2];
    const float* zr = (const float*)d_in[3];
    const float* dwt = (const float*)d_in[4];
    const float* bs = (const float*)d_in[5];
    float* Y = (float*)d_out;

    const size_t needB = (size_t)N_DIM * K_DIM * 2;   // 33.5 MB
    const size_t needA = (size_t)M_DIM * K_DIM * 2;   // 67.1 MB

    if (ws_size >= needA + needB) {
        unsigned char* Bpk = (unsigned char*)d_ws;
        unsigned char* Apk = Bpk + needB;
        k_pack_w<<<dim3((unsigned)(needB >> 12)), dim3(256), 0, stream>>>(qp, sc, zr, dwt, Bpk);
        k_pack_x<<<dim3((unsigned)(needA >> 12)), dim3(256), 0, stream>>>(X, Apk);
        k_gemm_b32<<<dim3((M_DIM / 256) * (N_DIM / 256)), dim3(512), 0, stream>>>(Apk, Bpk, bs, Y);
    } else {
        k_gemm_fused<<<dim3((M_DIM / 128) * (N_DIM / 128)), dim3(256), 0, stream>>>(
            X, qp, sc, zr, dwt, bs, Y);
    }
}

// Round 13
// 268.832 us; speedup vs baseline: 1.0643x; 1.0415x over previous
//
#include <hip/hip_runtime.h>

// y[m,o] = sum_k x[m,k] * (W[o,k] + dW[o,k]) + bias[o],  W int4-dequant.
// M=8192, N=4096(OUT), K=4096(IN).
//
// FINAL (= round 10, best of 12 rounds; 267.9 us total, GEMM 211 us,
// MfmaUtil 60.7%, LDS conflicts 0, absmax 0.125 = reference-noise floor).
//
// Structure:
//  Phase 1: two pack kernels (HBM-roofline-bound, ~57us):
//    k_pack_w: int4 dequant (q-z)*s + delta_weight -> bf16, written in
//      MFMA-FRAGMENT ORDER (16KB tiles of 16 x 1KB chunks; chunk=rowtile*2+ks,
//      within chunk lane=(row&15)+16*((k&31)>>3), bytes=(k&7)*2), with
//      OUTPUT-LINEAR gather addressing (both read+write coalesced).
//    k_pack_x: fp32 x -> bf16, same fragment packing.
//  Phase 2: 256x256-tile GEMM, bf16 mfma_f32_16x16x32, 8 waves (2Mx4N),
//    128KB LDS (2 bufs x {A0,A1,B0,B1} 16KB halves), global_load_lds
//    staging (linear, dest = tid*16), fragment ds_read_b128 = wave-uniform
//    base + immediate chunk offset + lane*16 -> conflict-free by
//    construction. 8-phase schedule, 4 barriers + 2 counted vmcnt(4)/iter
//    (liveness-derived; validated r4/r7/r10). XCD-bijective block swizzle.
//
// Numerics: single-term bf16 GEMM. Measured absmax is 0.125 for the exact
// 3-term split (r1) AND all 1-term variants -> 0.125 is reference-side
// (XLA einsum) noise; bf16 rounding contributes ~2^-5 max, invisible.

#define M_DIM 8192
#define N_DIM 4096
#define K_DIM 4096
#define NUMEL (N_DIM * K_DIM)

typedef _Float16 half_t;
typedef __attribute__((ext_vector_type(4))) _Float16 half4v;
typedef __attribute__((ext_vector_type(8))) _Float16 half8v;
typedef __attribute__((ext_vector_type(8))) short short8v;
typedef __attribute__((ext_vector_type(8))) unsigned short ushort8v;
typedef __attribute__((ext_vector_type(4))) float float4v;
typedef __attribute__((ext_vector_type(4))) int int4v;

#define KTILES 64                // K/64
#define LDT 72                   // fused-fallback padded row stride

static __device__ __forceinline__ void gload16(const void* g, void* l) {
    __builtin_amdgcn_global_load_lds(
        (const __attribute__((address_space(1))) void*)g,
        (__attribute__((address_space(3))) void*)l, 16, 0, 0);
}

// float -> bf16 bits, round-to-nearest-even (inputs are finite, well-scaled)
static __device__ __forceinline__ unsigned short f2bf(float f) {
    unsigned u = __builtin_bit_cast(unsigned, f);
    u += 0x7fffu + ((u >> 16) & 1u);
    return (unsigned short)(u >> 16);
}

// ---------- Phase 1a: dequant+delta -> bf16, fragment-packed (gather) ------
__global__ __launch_bounds__(256) void k_pack_w(
    const int* __restrict__ qp, const float* __restrict__ sc,
    const float* __restrict__ zr, const float* __restrict__ dwt,
    unsigned char* __restrict__ Wp)
{
    const size_t o = ((size_t)blockIdx.x * 256 + threadIdx.x) << 4;
    const int chunk16 = (int)(o >> 14);          // panel*64 + kt
    const int c  = (int)(o >> 10) & 15;          // rt*2 + ks
    const int ln = (int)(o >> 4) & 63;
    const int n = (chunk16 >> 6) * 128 + (c >> 1) * 16 + (ln & 15);
    const int k = (chunk16 & 63) * 64 + (c & 1) * 32 + (ln >> 4) * 8;
    const long flat = (long)n * K_DIM + k;
    const int g = n * 32 + (k >> 7);
    const float s = sc[g];
    const float zs = zr[g] * s;
    int4v q4 = *(const int4v*)(qp + (flat >> 1));
    float4v d0 = *(const float4v*)(dwt + flat);
    float4v d1 = *(const float4v*)(dwt + flat + 4);
    float d[8] = {d0[0], d0[1], d0[2], d0[3], d1[0], d1[1], d1[2], d1[3]};
    ushort8v vh;
#pragma unroll
    for (int j = 0; j < 4; ++j) {
        vh[2*j]   = f2bf(fmaf((float)(q4[j] & 15),        s, d[2*j]   - zs));
        vh[2*j+1] = f2bf(fmaf((float)((q4[j] >> 4) & 15), s, d[2*j+1] - zs));
    }
    *(ushort8v*)(Wp + o) = vh;
}

// ---------- Phase 1b: x fp32 -> bf16, fragment-packed (gather) ----------
__global__ __launch_bounds__(256) void k_pack_x(
    const float* __restrict__ X, unsigned char* __restrict__ Xp)
{
    const size_t o = ((size_t)blockIdx.x * 256 + threadIdx.x) << 4;
    const int chunk16 = (int)(o >> 14);
    const int c  = (int)(o >> 10) & 15;
    const int ln = (int)(o >> 4) & 63;
    const int m = (chunk16 >> 6) * 128 + (c >> 1) * 16 + (ln & 15);
    const int k = (chunk16 & 63) * 64 + (c & 1) * 32 + (ln >> 4) * 8;
    const float* src = X + (size_t)m * K_DIM + k;
    float4v x0 = *(const float4v*)(src);
    float4v x1 = *(const float4v*)(src + 4);
    ushort8v vh;
    vh[0] = f2bf(x0[0]); vh[1] = f2bf(x0[1]);
    vh[2] = f2bf(x0[2]); vh[3] = f2bf(x0[3]);
    vh[4] = f2bf(x1[0]); vh[5] = f2bf(x1[1]);
    vh[6] = f2bf(x1[2]); vh[7] = f2bf(x1[3]);
    *(ushort8v*)(Xp + o) = vh;
}

// ---------- 8-phase 256x256 GEMM, bf16 16x16x32, frag-packed ----------
#define BARX() do { __builtin_amdgcn_sched_barrier(0); \
                    __builtin_amdgcn_s_barrier(); \
                    __builtin_amdgcn_sched_barrier(0); } while(0)
#define WAITV(N) do { asm volatile("s_waitcnt vmcnt(" #N ")" ::: "memory"); \
                      __builtin_amdgcn_sched_barrier(0); } while(0)

#define READ_A(BUF, F0) do { \
_Pragma("unroll") for (int i_ = 0; i_ < 4; ++i_) \
_Pragma("unroll") for (int ks_ = 0; ks_ < 2; ++ks_) \
        ah[i_][ks_] = *(const short8v*)(&lds[BUF][wm] \
            [((((F0) + i_) * 2 + ks_) << 10) + lane16]); \
    } while(0)

#define READ_B(BUF, DST, J0) do { \
_Pragma("unroll") for (int j_ = 0; j_ < 2; ++j_) \
_Pragma("unroll") for (int ks_ = 0; ks_ < 2; ++ks_) \
        DST[j_][ks_] = *(const short8v*)(&lds[BUF][bhalf] \
            [bq8192 + ((((J0) + j_) * 2 + ks_) << 10) + lane16]); \
    } while(0)

#define MFMA_Q(F0, N0, BREG) do { \
    __builtin_amdgcn_s_setprio(1); \
_Pragma("unroll") for (int i_ = 0; i_ < 4; ++i_) \
_Pragma("unroll") for (int j_ = 0; j_ < 2; ++j_) \
_Pragma("unroll") for (int ks_ = 0; ks_ < 2; ++ks_) \
        acc[(F0)+i_][(N0)+j_] = __builtin_amdgcn_mfma_f32_16x16x32_bf16( \
            ah[i_][ks_], BREG[j_][ks_], acc[(F0)+i_][(N0)+j_], 0, 0, 0); \
    __builtin_amdgcn_s_setprio(0); \
} while(0)

__global__ __launch_bounds__(512, 2) void k_gemm8ph(
    const unsigned char* __restrict__ Apk, const unsigned char* __restrict__ Bpk,
    const float* __restrict__ bias, float* __restrict__ Y)
{
    __shared__ __align__(16) unsigned char lds[2][4][16384];  // [buf][A0,A1,B0,B1]

    const int tid  = threadIdx.x;
    const int lane = tid & 63;
    const int wave = tid >> 6;
    const int wm = wave >> 2;
    const int wn = wave & 3;
    const int bhalf = 2 + (wn >> 1);
    const int bq8192 = (wn & 1) << 13;     // wave's 8KB quarter within B half
    const int lane16 = lane << 4;

    const int wg = blockIdx.x;
    const int swg = (wg & 7) * 64 + (wg >> 3);   // 512 blocks, 8 XCDs, bijective
    const int bn = swg & 15;
    const int bm = swg >> 4;

    auto asrc = [&](int h, int tk) {
        return Apk + ((((size_t)(2 * bm + h)) * KTILES + tk) << 14);
    };
    auto bsrc = [&](int h, int tk) {
        return Bpk + ((((size_t)(2 * bn + h)) * KTILES + tk) << 14);
    };
    auto stageh = [&](int b, int h, const unsigned char* s) {
        unsigned char* d = &lds[b][h][tid << 4];
        gload16(s + (tid << 4), d);
        gload16(s + 8192 + (tid << 4), d + 8192);
    };

    short8v ah[4][2], b01[2][2], b23[2][2];
    float4v acc[8][4];
    const float4v zero4 = {0.f, 0.f, 0.f, 0.f};
#pragma unroll
    for (int i = 0; i < 8; ++i)
#pragma unroll
        for (int j = 0; j < 4; ++j) acc[i][j] = zero4;

    // ---- prologue: tile0 -> buf0 (4 halves); B(tile1) -> buf1 ----
    stageh(0, 0, asrc(0, 0)); stageh(0, 1, asrc(1, 0));
    stageh(0, 2, bsrc(0, 0)); stageh(0, 3, bsrc(1, 0));
    stageh(1, 2, bsrc(0, 1)); stageh(1, 3, bsrc(1, 1));
    WAITV(4);
    BARX();

    for (int it = 0; it < 31; ++it) {
        const int t1 = 2 * it + 1, t2 = 2 * it + 2, t3 = 2 * it + 3;
        // p0: read buf0 A[0-3],B[0-1]; stage S0 = A(buf1,t1)   [no barrier]
        READ_A(0, 0); READ_B(0, b01, 0);
        stageh(1, 0, asrc(0, t1)); stageh(1, 1, asrc(1, t1));
        MFMA_Q(0, 0, b01);
        // p1: read B[2-3](buf0)                                 [no barrier]
        READ_B(0, b23, 2);
        MFMA_Q(0, 2, b23);
        // p2: read A[4-7](buf0)
        READ_A(0, 4);
        BARX();
        MFMA_Q(4, 2, b23);
        // p3: stage S3 = B(buf0,t2); drain for buf1 t1
        stageh(0, 2, bsrc(0, t2)); stageh(0, 3, bsrc(1, t2));
        WAITV(4);
        BARX();
        MFMA_Q(4, 0, b01);
        // p4: read buf1 A[0-3],B[0-1]; stage S4 = A(buf0,t2)    [no barrier]
        READ_A(1, 0); READ_B(1, b01, 0);
        stageh(0, 0, asrc(0, t2)); stageh(0, 1, asrc(1, t2));
        MFMA_Q(0, 0, b01);
        // p5                                                    [no barrier]
        READ_B(1, b23, 2);
        MFMA_Q(0, 2, b23);
        // p6
        READ_A(1, 4);
        BARX();
        MFMA_Q(4, 2, b23);
        // p7: stage S7 = B(buf1,t3); drain for buf0 t2
        stageh(1, 2, bsrc(0, t3)); stageh(1, 3, bsrc(1, t3));
        WAITV(4);
        BARX();
        MFMA_Q(4, 0, b01);
    }

    // ---- tail: K-tiles 62 (buf0), 63 (buf1); conservative barriers ----
    READ_A(0, 0); READ_B(0, b01, 0);
    stageh(1, 0, asrc(0, 63)); stageh(1, 1, asrc(1, 63));
    BARX(); MFMA_Q(0, 0, b01);
    READ_B(0, b23, 2);
    BARX(); MFMA_Q(0, 2, b23);
    READ_A(0, 4);
    BARX(); MFMA_Q(4, 2, b23);
    WAITV(0);                      // drain: buf1 tile63 fully staged
    BARX(); MFMA_Q(4, 0, b01);
    READ_A(1, 0); READ_B(1, b01, 0);
    BARX(); MFMA_Q(0, 0, b01);
    READ_B(1, b23, 2);
    BARX(); MFMA_Q(0, 2, b23);
    READ_A(1, 4);
    BARX(); MFMA_Q(4, 2, b23);
    MFMA_Q(4, 0, b01);

    // ---- epilogue: 16x16 C/D map col=lane&15, row=(lane>>4)*4+reg ----
    const long m0 = (long)bm * 256 + wm * 128;
    const long n0 = (long)bn * 256 + wn * 64;
#pragma unroll
    for (int mf = 0; mf < 8; ++mf) {
        const long row = m0 + mf * 16 + (lane >> 4) * 4;
#pragma unroll
        for (int nf = 0; nf < 4; ++nf) {
            const long col = n0 + nf * 16 + (lane & 15);
            const float b = bias[col];
#pragma unroll
            for (int r = 0; r < 4; ++r)
                Y[(row + r) * N_DIM + col] = acc[mf][nf][r] + b;
        }
    }
}

// ---------- fallback (no workspace): fused dequant 128x128 GEMM ----------
__global__ __launch_bounds__(256, 2) void k_gemm_fused(
    const float* __restrict__ X, const int* __restrict__ qp,
    const float* __restrict__ sc, const float* __restrict__ zr,
    const float* __restrict__ dwt,
    const float* __restrict__ bias, float* __restrict__ Y)
{
    __shared__ __align__(16) half_t Ah[128 * LDT];
    __shared__ __align__(16) half_t Bh[128 * LDT];

    const int tid  = threadIdx.x;
    const int lane = tid & 63;
    const int wave = tid >> 6;
    const int wm = wave >> 1, wn = wave & 1;
    const int bn = blockIdx.x & 31;
    const int bm = blockIdx.x >> 5;
    const long m0 = (long)bm * 128;
    const long n0 = (long)bn * 128;
    const int fr = lane & 15;
    const int ko = (lane >> 4) * 8;

    const float4v zero4 = {0.f, 0.f, 0.f, 0.f};
    float4v acc[4][4];
#pragma unroll
    for (int i = 0; i < 4; ++i)
#pragma unroll
        for (int j = 0; j < 4; ++j) acc[i][j] = zero4;

    for (int k0 = 0; k0 < K_DIM; k0 += 64) {
        {
            const int ar = tid >> 4;
            const int ac = (tid & 15) * 4;
#pragma unroll
            for (int rr = 0; rr < 8; ++rr) {
                const int row = ar + rr * 16;
                float4v xv = *(const float4v*)(X + (m0 + row) * K_DIM + k0 + ac);
                half4v h;
#pragma unroll
                for (int j = 0; j < 4; ++j) h[j] = (half_t)xv[j];
                *(half4v*)(Ah + row * LDT + ac) = h;
            }
        }
        {
            const int cr = tid >> 3;
            const int cc = (tid & 7) * 8;
#pragma unroll
            for (int rr = 0; rr < 4; ++rr) {
                const int row = cr + rr * 32;
                const long n = n0 + row;
                const int g = (int)(n * 32 + (k0 >> 7));
                const float s = sc[g];
                const float zs = zr[g] * s;
                const long flat = n * K_DIM + k0 + cc;
                int4v q4 = *(const int4v*)(qp + (flat >> 1));
                float4v d0 = *(const float4v*)(dwt + flat);
                float4v d1 = *(const float4v*)(dwt + flat + 4);
                float d[8] = {d0[0], d0[1], d0[2], d0[3], d1[0], d1[1], d1[2], d1[3]};
                half8v vh;
#pragma unroll
                for (int j = 0; j < 4; ++j) {
                    vh[2*j]   = (half_t)fmaf((float)(q4[j] & 15),        s, d[2*j]   - zs);
                    vh[2*j+1] = (half_t)fmaf((float)((q4[j] >> 4) & 15), s, d[2*j+1] - zs);
                }
                *(half8v*)(Bh + row * LDT + cc) = vh;
            }
        }
        __syncthreads();
#pragma unroll
        for (int ks = 0; ks < 2; ++ks) {
            const int kk = ks * 32 + ko;
            half8v a2[4], b2[4];
#pragma unroll
            for (int i = 0; i < 4; ++i) {
                a2[i] = *(const half8v*)(Ah + (wm * 64 + i * 16 + fr) * LDT + kk);
                b2[i] = *(const half8v*)(Bh + (wn * 64 + i * 16 + fr) * LDT + kk);
            }
#pragma unroll
            for (int i = 0; i < 4; ++i)
#pragma unroll
                for (int j = 0; j < 4; ++j)
                    acc[i][j] = __builtin_amdgcn_mfma_f32_16x16x32_f16(
                        a2[i], b2[j], acc[i][j], 0, 0, 0);
        }
        __syncthreads();
    }

#pragma unroll
    for (int i = 0; i < 4; ++i) {
        const long mrow = m0 + wm * 64 + i * 16 + (lane >> 4) * 4;
#pragma unroll
        for (int j = 0; j < 4; ++j) {
            const long col = n0 + wn * 64 + j * 16 + (lane & 15);
            const float b = bias[col];
#pragma unroll
            for (int r = 0; r < 4; ++r)
                Y[(mrow + r) * N_DIM + col] = acc[i][j][r] + b;
        }
    }
}

extern "C" void kernel_launch(void* const* d_in, const int* in_sizes, int n_in,
                              void* d_out, int out_size, void* d_ws, size_t ws_size,
                              hipStream_t stream)
{
    const float* X  = (const float*)d_in[0];
    const int*   qp = (const int*)d_in[1];
    const float* sc = (const float*)d_in[2];
    const float* zr = (const float*)d_in[3];
    const float* dwt = (const float*)d_in[4];
    const float* bs = (const float*)d_in[5];
    float* Y = (float*)d_out;

    const size_t needB = (size_t)N_DIM * K_DIM * 2;   // 33.5 MB
    const size_t needA = (size_t)M_DIM * K_DIM * 2;   // 67.1 MB

    if (ws_size >= needA + needB) {
        unsigned char* Bpk = (unsigned char*)d_ws;
        unsigned char* Apk = Bpk + needB;
        k_pack_w<<<dim3((unsigned)(needB >> 12)), dim3(256), 0, stream>>>(qp, sc, zr, dwt, Bpk);
        k_pack_x<<<dim3((unsigned)(needA >> 12)), dim3(256), 0, stream>>>(X, Apk);
        k_gemm8ph<<<dim3((M_DIM / 256) * (N_DIM / 256)), dim3(512), 0, stream>>>(Apk, Bpk, bs, Y);
    } else {
        k_gemm_fused<<<dim3((M_DIM / 128) * (N_DIM / 128)), dim3(256), 0, stream>>>(
            X, qp, sc, zr, dwt, bs, Y);
    }
}